// Round 1
// baseline (889.110 us; speedup 1.0000x reference)
//
#include <hip/hip_runtime.h>

typedef unsigned short u16;
typedef unsigned int u32;
typedef __attribute__((ext_vector_type(4))) float f32x4;
typedef __attribute__((ext_vector_type(4))) u16 u16x4;
typedef __attribute__((ext_vector_type(8))) u16 u16x8;
typedef __attribute__((ext_vector_type(8))) __bf16 bf16x8;

#define FLA_EPS 1e-6f

__device__ __forceinline__ u16 f2b(float f) {
  union { float f; u32 u; } v; v.f = f;
  u32 r = v.u + 0x7FFFu + ((v.u >> 16) & 1u);
  return (u16)(r >> 16);
}
__device__ __forceinline__ float b2f(u16 h) {
  union { u32 u; float f; } v; v.u = ((u32)h) << 16; return v.f;
}
// async global->LDS, 16B per lane; LDS dest must be wave-uniform base + lane*16
__device__ __forceinline__ void g2l16(const void* g, void* l) {
  __builtin_amdgcn_global_load_lds((__attribute__((address_space(1))) void*)g,
                                   (__attribute__((address_space(3))) void*)l,
                                   16, 0, 0);
}

// ---------------- cast x fp32 -> bf16 (8 elems/thread, exact grid) ----------------
__global__ void __launch_bounds__(256) cast_f32_bf16(const float* __restrict__ in,
                                                     u16* __restrict__ out) {
  size_t i = (size_t)blockIdx.x * 256 + threadIdx.x;   // one u16x8 per thread
  const f32x4* p = (const f32x4*)in + i * 2;
  f32x4 a = p[0], b = p[1];
  u16x8 r;
  r[0] = f2b(a[0]); r[1] = f2b(a[1]); r[2] = f2b(a[2]); r[3] = f2b(a[3]);
  r[4] = f2b(b[0]); r[5] = f2b(b[1]); r[6] = f2b(b[2]); r[7] = f2b(b[3]);
  ((u16x8*)out)[i] = r;
}

// ---------------- transpose + cast: Wt[n][k] = bf16(W[k][n]) ----------------
__global__ void __launch_bounds__(256) transpose_cast(const float* __restrict__ W,
                                                      u16* __restrict__ Wt, int dim) {
  __shared__ float tile[64][65];
  const int t = threadIdx.x;
  const int k0 = blockIdx.x * 64, n0 = blockIdx.y * 64;
  const int r = t >> 4, c4 = (t & 15) * 4;
#pragma unroll
  for (int i = 0; i < 4; ++i) {
    f32x4 vv = *(const f32x4*)(W + (size_t)(k0 + r + i * 16) * dim + n0 + c4);
    tile[r + i * 16][c4 + 0] = vv[0];
    tile[r + i * 16][c4 + 1] = vv[1];
    tile[r + i * 16][c4 + 2] = vv[2];
    tile[r + i * 16][c4 + 3] = vv[3];
  }
  __syncthreads();
#pragma unroll
  for (int i = 0; i < 4; ++i) {
    int nrow = r + i * 16;
    u16x4 o;
#pragma unroll
    for (int j = 0; j < 4; ++j) o[j] = f2b(tile[c4 + j][nrow]);
    *(u16x4*)(Wt + (size_t)(n0 + nrow) * dim + k0 + c4) = o;
  }
}

// ---------------- 128x128 bf16 MFMA GEMM, Bt = B^T [N][K]; C bf16 or fp32+bias ----------------
template <bool FINAL>
__global__ void __launch_bounds__(256) gemm_bt(const u16* __restrict__ A,
                                               const u16* __restrict__ Bt,
                                               void* __restrict__ Cout,
                                               const float* __restrict__ bias,
                                               int M, int N, int K) {
  __shared__ __align__(16) u16 As[128 * 64];
  __shared__ __align__(16) u16 Bs[128 * 64];
  const int t = threadIdx.x;
  const int m0 = blockIdx.x * 128, n0 = blockIdx.y * 128;
  const int w = t >> 6, l = t & 63, quad = l >> 4, lr = l & 15;
  const int wm = (w >> 1) * 64, wn = (w & 1) * 64;
  const int trow = t >> 3, tcol = (t & 7) * 8;
  f32x4 acc[4][4] = {};
  for (int k0 = 0; k0 < K; k0 += 64) {
#pragma unroll
    for (int i = 0; i < 4; ++i) {
      int r = i * 32 + trow;
      g2l16(A + (size_t)(m0 + r) * K + k0 + tcol, &As[r * 64 + tcol]);
      g2l16(Bt + (size_t)(n0 + r) * K + k0 + tcol, &Bs[r * 64 + tcol]);
    }
    __syncthreads();
#pragma unroll
    for (int ks = 0; ks < 2; ++ks) {
      bf16x8 af[4], bfr[4];
#pragma unroll
      for (int i = 0; i < 4; ++i) {
        af[i] = *(const bf16x8*)&As[(wm + i * 16 + lr) * 64 + ks * 32 + quad * 8];
        bfr[i] = *(const bf16x8*)&Bs[(wn + i * 16 + lr) * 64 + ks * 32 + quad * 8];
      }
#pragma unroll
      for (int i = 0; i < 4; ++i)
#pragma unroll
        for (int j = 0; j < 4; ++j)
          acc[i][j] = __builtin_amdgcn_mfma_f32_16x16x32_bf16(af[i], bfr[j], acc[i][j], 0, 0, 0);
    }
    __syncthreads();
  }
#pragma unroll
  for (int i = 0; i < 4; ++i)
#pragma unroll
    for (int j = 0; j < 4; ++j) {
      int col = n0 + wn + j * 16 + lr;
#pragma unroll
      for (int r = 0; r < 4; ++r) {
        int row = m0 + wm + i * 16 + quad * 4 + r;
        float v = acc[i][j][r];
        if (FINAL) ((float*)Cout)[(size_t)row * N + col] = v + bias[col];
        else       ((u16*)Cout)[(size_t)row * N + col] = f2b(v);
      }
    }
}

// ---------------- feature map: X[:, h*64:h*64+64] = relu(X_h @ proj) + eps, in place ----------------
__global__ void __launch_bounds__(256) feature_map(u16* __restrict__ qbuf,
                                                   u16* __restrict__ kbuf,
                                                   const u16* __restrict__ projT) {
  __shared__ __align__(16) u16 As[128 * 64];
  __shared__ __align__(16) u16 Bs[64 * 64];
  const int t = threadIdx.x;
  u16* base = blockIdx.z ? kbuf : qbuf;
  const size_t tok0 = (size_t)blockIdx.x * 128;
  const int h = blockIdx.y;
  const int w = t >> 6, l = t & 63, quad = l >> 4, lr = l & 15;
  const int trow = t >> 3, tcol = (t & 7) * 8;
#pragma unroll
  for (int i = 0; i < 4; ++i) {
    int r = i * 32 + trow;
    g2l16(base + (tok0 + r) * 1024 + h * 64 + tcol, &As[r * 64 + tcol]);
  }
#pragma unroll
  for (int i = 0; i < 2; ++i) {
    int r = i * 32 + trow;
    g2l16(projT + (size_t)r * 64 + tcol, &Bs[r * 64 + tcol]);
  }
  __syncthreads();
  f32x4 acc[2][4] = {};
  const int wrow = w * 32;
#pragma unroll
  for (int ks = 0; ks < 2; ++ks) {
    bf16x8 af[2], bfr[4];
#pragma unroll
    for (int i = 0; i < 2; ++i)
      af[i] = *(const bf16x8*)&As[(wrow + i * 16 + lr) * 64 + ks * 32 + quad * 8];
#pragma unroll
    for (int j = 0; j < 4; ++j)
      bfr[j] = *(const bf16x8*)&Bs[(j * 16 + lr) * 64 + ks * 32 + quad * 8];
#pragma unroll
    for (int i = 0; i < 2; ++i)
#pragma unroll
      for (int j = 0; j < 4; ++j)
        acc[i][j] = __builtin_amdgcn_mfma_f32_16x16x32_bf16(af[i], bfr[j], acc[i][j], 0, 0, 0);
  }
#pragma unroll
  for (int i = 0; i < 2; ++i)
#pragma unroll
    for (int j = 0; j < 4; ++j)
#pragma unroll
      for (int r = 0; r < 4; ++r) {
        float v = fmaxf(acc[i][j][r], 0.0f) + FLA_EPS;
        size_t tok = tok0 + wrow + i * 16 + quad * 4 + r;
        base[tok * 1024 + h * 64 + j * 16 + lr] = f2b(v);
      }
}

// ---------------- kv partials: part[bh][sub][d][f] = sum_n kf[n][f]*v[n][d] over 256 n ----------------
__global__ void __launch_bounds__(256) kv_partial(const u16* __restrict__ kf,
                                                  const u16* __restrict__ v,
                                                  float* __restrict__ part,
                                                  float* __restrict__ ksum_p) {
  const int t = threadIdx.x;
  const int bh = blockIdx.x, b = bh >> 4, h = bh & 15;
  const int w = t >> 6, l = t & 63;
  const int sub = blockIdx.y * 4 + w;                 // 0..31
  const int f0 = (l >> 3) * 8, d0 = (l & 7) * 8;
  const size_t rowbase = ((size_t)b * 8192 + (size_t)sub * 256) * 1024 + h * 64;
  float acc[8][8] = {};
  float ks[8] = {};
#pragma unroll 2
  for (int n = 0; n < 256; ++n) {
    u16x8 ka = *(const u16x8*)(kf + rowbase + (size_t)n * 1024 + f0);
    u16x8 va = *(const u16x8*)(v + rowbase + (size_t)n * 1024 + d0);
    float kff[8], vf[8];
#pragma unroll
    for (int i = 0; i < 8; ++i) { kff[i] = b2f(ka[i]); vf[i] = b2f(va[i]); }
#pragma unroll
    for (int i = 0; i < 8; ++i) {
      ks[i] += kff[i];
#pragma unroll
      for (int j = 0; j < 8; ++j) acc[i][j] = fmaf(kff[i], vf[j], acc[i][j]);
    }
  }
  float* pb = part + ((size_t)bh * 32 + sub) * 4096;
#pragma unroll
  for (int j = 0; j < 8; ++j)
#pragma unroll
    for (int i = 0; i < 8; i += 4) {
      f32x4 vv = { acc[i][j], acc[i + 1][j], acc[i + 2][j], acc[i + 3][j] };
      *(f32x4*)(pb + (d0 + j) * 64 + f0 + i) = vv;   // part[d][f] = kv[f][d]
    }
  if (d0 == 0) {
    float* kp = ksum_p + ((size_t)bh * 32 + sub) * 64 + f0;
    f32x4 a = { ks[0], ks[1], ks[2], ks[3] }, bq = { ks[4], ks[5], ks[6], ks[7] };
    *(f32x4*)(kp) = a; *(f32x4*)(kp + 4) = bq;
  }
}

// ---------------- reduce kv partials over 32 subs ----------------
__global__ void __launch_bounds__(256) reduce_kv(const float* __restrict__ part,
                                                 float* __restrict__ kvT) {
  int i = blockIdx.x * 256 + threadIdx.x;             // 262144 total
  int bh = i >> 12, dfi = i & 4095;
  const float* p = part + (size_t)bh * 32 * 4096 + dfi;
  float s = 0.f;
#pragma unroll
  for (int sub = 0; sub < 32; ++sub) s += p[(size_t)sub * 4096];
  kvT[i] = s;
}

// ---------------- num/den + normalize: out = (qf @ kv) / (qf . ksum + eps) ----------------
__global__ void __launch_bounds__(256) num_den(const u16* __restrict__ qf,
                                               const float* __restrict__ kvT,
                                               const float* __restrict__ ksum_p,
                                               u16* __restrict__ outI) {
  __shared__ __align__(16) u16 As[128 * 64];
  __shared__ __align__(16) u16 Bs[64 * 64];
  __shared__ float ksum_s[64];
  __shared__ float den_s[128];
  const int t = threadIdx.x;
  const size_t tok0 = (size_t)blockIdx.x * 128;
  const int h = blockIdx.y;
  const int bh = (blockIdx.x >> 6) * 16 + h;
  const int w = t >> 6, l = t & 63, quad = l >> 4, lr = l & 15;
  const int trow = t >> 3, tcol = (t & 7) * 8;
#pragma unroll
  for (int i = 0; i < 4; ++i) {
    int r = i * 32 + trow;
    g2l16(qf + (tok0 + r) * 1024 + h * 64 + tcol, &As[r * 64 + tcol]);
  }
  {  // stage kv^T (fp32 [d][f]) into Bs bf16 [d][f]
    const float* kvb = kvT + (size_t)bh * 4096;
    int d = t >> 2, cb = (t & 3) * 16;
    u16x8 o0, o1;
#pragma unroll
    for (int q4 = 0; q4 < 2; ++q4) {
      f32x4 vv = *(const f32x4*)(kvb + d * 64 + cb + q4 * 4);
      o0[q4 * 4 + 0] = f2b(vv[0]); o0[q4 * 4 + 1] = f2b(vv[1]);
      o0[q4 * 4 + 2] = f2b(vv[2]); o0[q4 * 4 + 3] = f2b(vv[3]);
    }
#pragma unroll
    for (int q4 = 0; q4 < 2; ++q4) {
      f32x4 vv = *(const f32x4*)(kvb + d * 64 + cb + 8 + q4 * 4);
      o1[q4 * 4 + 0] = f2b(vv[0]); o1[q4 * 4 + 1] = f2b(vv[1]);
      o1[q4 * 4 + 2] = f2b(vv[2]); o1[q4 * 4 + 3] = f2b(vv[3]);
    }
    *(u16x8*)&Bs[d * 64 + cb] = o0;
    *(u16x8*)&Bs[d * 64 + cb + 8] = o1;
  }
  if (t < 64) {  // reduce ksum partials
    float s = 0.f;
    const float* kp = ksum_p + (size_t)bh * 32 * 64 + t;
#pragma unroll
    for (int sub = 0; sub < 32; ++sub) s += kp[(size_t)sub * 64];
    ksum_s[t] = s;
  }
  __syncthreads();
  if (t < 128) {  // den per token row (rotated f to dodge bank conflicts)
    float d = FLA_EPS;
#pragma unroll
    for (int jj = 0; jj < 64; ++jj) {
      int f = (t + jj) & 63;
      d += b2f(As[t * 64 + f]) * ksum_s[f];
    }
    den_s[t] = d;
  }
  __syncthreads();
  f32x4 acc[2][4] = {};
  const int wrow = w * 32;
#pragma unroll
  for (int ks = 0; ks < 2; ++ks) {
    bf16x8 af[2], bfr[4];
#pragma unroll
    for (int i = 0; i < 2; ++i)
      af[i] = *(const bf16x8*)&As[(wrow + i * 16 + lr) * 64 + ks * 32 + quad * 8];
#pragma unroll
    for (int j = 0; j < 4; ++j)
      bfr[j] = *(const bf16x8*)&Bs[(j * 16 + lr) * 64 + ks * 32 + quad * 8];
#pragma unroll
    for (int i = 0; i < 2; ++i)
#pragma unroll
      for (int j = 0; j < 4; ++j)
        acc[i][j] = __builtin_amdgcn_mfma_f32_16x16x32_bf16(af[i], bfr[j], acc[i][j], 0, 0, 0);
  }
#pragma unroll
  for (int i = 0; i < 2; ++i)
#pragma unroll
    for (int j = 0; j < 4; ++j)
#pragma unroll
      for (int r = 0; r < 4; ++r) {
        int rloc = wrow + i * 16 + quad * 4 + r;
        float v = acc[i][j][r] / den_s[rloc];
        outI[(tok0 + rloc) * 1024 + h * 64 + j * 16 + lr] = f2b(v);
      }
}

extern "C" void kernel_launch(void* const* d_in, const int* in_sizes, int n_in,
                              void* d_out, int out_size, void* d_ws, size_t ws_size,
                              hipStream_t stream) {
  const float* x    = (const float*)d_in[0];
  const float* Wq   = (const float*)d_in[1];
  const float* Wk   = (const float*)d_in[2];
  const float* Wv   = (const float*)d_in[3];
  const float* proj = (const float*)d_in[4];
  const float* Wo   = (const float*)d_in[5];
  const float* bo   = (const float*)d_in[6];
  float* out = (float*)d_out;

  char* ws = (char*)d_ws;
  const size_t SZ = 1ull << 26;            // 64 MiB per activation buffer
  u16* xb    = (u16*)(ws + 0);             // also reused as out_inner
  u16* qb    = (u16*)(ws + SZ);
  u16* kb    = (u16*)(ws + 2 * SZ);
  u16* vb    = (u16*)(ws + 3 * SZ);
  u16* wqT   = (u16*)(ws + 4 * SZ);
  u16* wkT   = (u16*)(ws + 4 * SZ + 0x200000);
  u16* wvT   = (u16*)(ws + 4 * SZ + 0x400000);
  u16* woT   = (u16*)(ws + 4 * SZ + 0x600000);
  u16* projT = (u16*)(ws + 4 * SZ + 0x800000);
  float* part   = (float*)(ws + 4 * SZ + 0x810000);              // 32 MiB
  float* ksum_p = (float*)(ws + 4 * SZ + 0x810000 + 0x2000000);  // 512 KiB
  float* kvT    = (float*)(ws + 4 * SZ + 0x810000 + 0x2080000);  // 1 MiB

  // 1. casts / transposes
  cast_f32_bf16<<<16384, 256, 0, stream>>>(x, xb);
  transpose_cast<<<dim3(16, 16), 256, 0, stream>>>(Wq, wqT, 1024);
  transpose_cast<<<dim3(16, 16), 256, 0, stream>>>(Wk, wkT, 1024);
  transpose_cast<<<dim3(16, 16), 256, 0, stream>>>(Wv, wvT, 1024);
  transpose_cast<<<dim3(16, 16), 256, 0, stream>>>(Wo, woT, 1024);
  transpose_cast<<<dim3(1, 1), 256, 0, stream>>>(proj, projT, 64);
  // 2. QKV projections
  gemm_bt<false><<<dim3(256, 8), 256, 0, stream>>>(xb, wqT, qb, nullptr, 32768, 1024, 1024);
  gemm_bt<false><<<dim3(256, 8), 256, 0, stream>>>(xb, wkT, kb, nullptr, 32768, 1024, 1024);
  gemm_bt<false><<<dim3(256, 8), 256, 0, stream>>>(xb, wvT, vb, nullptr, 32768, 1024, 1024);
  // 3. feature maps (in place): qb->qf, kb->kf
  feature_map<<<dim3(256, 16, 2), 256, 0, stream>>>(qb, kb, projT);
  // 4. kv + ksum reduction
  kv_partial<<<dim3(64, 8), 256, 0, stream>>>(kb, vb, part, ksum_p);
  reduce_kv<<<1024, 256, 0, stream>>>(part, kvT);
  // 5. num/den + normalize -> out_inner (reuse xb)
  num_den<<<dim3(256, 16), 256, 0, stream>>>(qb, kvT, ksum_p, xb);
  // 6. output projection + bias
  gemm_bt<true><<<dim3(256, 8), 256, 0, stream>>>(xb, woT, out, bo, 32768, 1024, 1024);
}

// Round 2
// 812.158 us; speedup vs baseline: 1.0948x; 1.0948x over previous
//
#include <hip/hip_runtime.h>

typedef unsigned short u16;
typedef unsigned int u32;
typedef __attribute__((ext_vector_type(4))) float f32x4;
typedef __attribute__((ext_vector_type(4))) u16 u16x4;
typedef __attribute__((ext_vector_type(8))) u16 u16x8;
typedef __attribute__((ext_vector_type(8))) __bf16 bf16x8;

#define FLA_EPS 1e-6f

__device__ __forceinline__ u16 f2b(float f) {
  union { float f; u32 u; } v; v.f = f;
  u32 r = v.u + 0x7FFFu + ((v.u >> 16) & 1u);
  return (u16)(r >> 16);
}
__device__ __forceinline__ float b2f(u16 h) {
  union { u32 u; float f; } v; v.u = ((u32)h) << 16; return v.f;
}
__device__ __forceinline__ void g2l16(const void* g, void* l) {
  __builtin_amdgcn_global_load_lds((__attribute__((address_space(1))) void*)g,
                                   (__attribute__((address_space(3))) void*)l,
                                   16, 0, 0);
}

// ---------------- cast x fp32 -> bf16 ----------------
__global__ void __launch_bounds__(256) cast_f32_bf16(const float* __restrict__ in,
                                                     u16* __restrict__ out) {
  size_t i = (size_t)blockIdx.x * 256 + threadIdx.x;
  const f32x4* p = (const f32x4*)in + i * 2;
  f32x4 a = p[0], b = p[1];
  u16x8 r;
  r[0] = f2b(a[0]); r[1] = f2b(a[1]); r[2] = f2b(a[2]); r[3] = f2b(a[3]);
  r[4] = f2b(b[0]); r[5] = f2b(b[1]); r[6] = f2b(b[2]); r[7] = f2b(b[3]);
  ((u16x8*)out)[i] = r;
}

// ---------------- transpose + cast: Wt[n][k] = bf16(W[k][n]) ----------------
__global__ void __launch_bounds__(256) transpose_cast(const float* __restrict__ W,
                                                      u16* __restrict__ Wt, int dim) {
  __shared__ float tile[64][65];
  const int t = threadIdx.x;
  const int k0 = blockIdx.x * 64, n0 = blockIdx.y * 64;
  const int r = t >> 4, c4 = (t & 15) * 4;
#pragma unroll
  for (int i = 0; i < 4; ++i) {
    f32x4 vv = *(const f32x4*)(W + (size_t)(k0 + r + i * 16) * dim + n0 + c4);
    tile[r + i * 16][c4 + 0] = vv[0];
    tile[r + i * 16][c4 + 1] = vv[1];
    tile[r + i * 16][c4 + 2] = vv[2];
    tile[r + i * 16][c4 + 3] = vv[3];
  }
  __syncthreads();
#pragma unroll
  for (int i = 0; i < 4; ++i) {
    int nrow = r + i * 16;
    u16x4 o;
#pragma unroll
    for (int j = 0; j < 4; ++j) o[j] = f2b(tile[c4 + j][nrow]);
    *(u16x4*)(Wt + (size_t)(n0 + nrow) * dim + k0 + c4) = o;
  }
}

// ---------------- fold proj into Wq/Wk: WqkvT[sel*1024 + h*64 + f][k] = sum_d W[k][h*64+d]*proj[d][f]
__global__ void __launch_bounds__(256) fold_w(const float* __restrict__ Wq,
                                              const float* __restrict__ Wk,
                                              const float* __restrict__ proj,
                                              u16* __restrict__ WqkvT) {
  __shared__ float Wt[64][65];   // [k][d], padded
  __shared__ float P[64][64];    // [d][f] (broadcast reads)
  const int t = threadIdx.x;
  const int kbase = blockIdx.x * 64, h = blockIdx.y, sel = blockIdx.z;
  const float* W = sel ? Wk : Wq;
  {
    int row = t >> 2, cb = (t & 3) * 16;
#pragma unroll
    for (int i = 0; i < 4; ++i) {
      f32x4 vv = *(const f32x4*)(W + (size_t)(kbase + row) * 1024 + h * 64 + cb + i * 4);
      Wt[row][cb + i * 4 + 0] = vv[0]; Wt[row][cb + i * 4 + 1] = vv[1];
      Wt[row][cb + i * 4 + 2] = vv[2]; Wt[row][cb + i * 4 + 3] = vv[3];
      f32x4 pp = *(const f32x4*)(proj + (size_t)row * 64 + cb + i * 4);
      P[row][cb + i * 4 + 0] = pp[0]; P[row][cb + i * 4 + 1] = pp[1];
      P[row][cb + i * 4 + 2] = pp[2]; P[row][cb + i * 4 + 3] = pp[3];
    }
  }
  __syncthreads();
  const int kk = t & 63, fg = (t >> 6) * 16;
  float acc[16] = {};
  for (int d = 0; d < 64; ++d) {
    float w = Wt[kk][d];
#pragma unroll
    for (int ff = 0; ff < 16; ++ff) acc[ff] = fmaf(w, P[d][fg + ff], acc[ff]);
  }
#pragma unroll
  for (int ff = 0; ff < 16; ++ff)
    WqkvT[(size_t)(sel * 1024 + h * 64 + fg + ff) * 1024 + kbase + kk] = f2b(acc[ff]);
}

// ---------------- 128x128 bf16 MFMA GEMM, swizzled block order ----------------
// QKV: N = NGN*1024 = 3072, writes relu(.)+eps bf16 into q/k and plain bf16 into v.
// final: N = 1024, writes fp32 + bias.
template <int NGN, bool QKV>
__global__ void __launch_bounds__(256) gemm_swz(const u16* __restrict__ A,
                                                const u16* __restrict__ Bt,
                                                u16* __restrict__ qo, u16* __restrict__ ko,
                                                u16* __restrict__ vo,
                                                float* __restrict__ Cf,
                                                const float* __restrict__ bias) {
  __shared__ __align__(16) u16 As[128 * 64];
  __shared__ __align__(16) u16 Bs[128 * 64];
  const int t = threadIdx.x;
  // swizzle: 8x8 (m,n) block groups -> co-resident blocks share 8 A-strips + 8 B-strips (4 MB)
  const int flat = blockIdx.x + blockIdx.y * 256;
  const int g = flat >> 6, r_ = flat & 63;
  const int gm = g / NGN, gn = g - gm * NGN;
  const int m0 = (gm * 8 + (r_ & 7)) * 128;
  const int n0 = (gn * 8 + (r_ >> 3)) * 128;
  const int w = t >> 6, l = t & 63, quad = l >> 4, lr = l & 15;
  const int wm = (w >> 1) * 64, wn = (w & 1) * 64;
  const int trow = t >> 3, tcol = (t & 7) * 8;
  f32x4 acc[4][4] = {};
  for (int k0 = 0; k0 < 1024; k0 += 64) {
#pragma unroll
    for (int i = 0; i < 4; ++i) {
      int r = i * 32 + trow;
      g2l16(A + (size_t)(m0 + r) * 1024 + k0 + tcol, &As[r * 64 + tcol]);
      g2l16(Bt + (size_t)(n0 + r) * 1024 + k0 + tcol, &Bs[r * 64 + tcol]);
    }
    __syncthreads();
#pragma unroll
    for (int ks = 0; ks < 2; ++ks) {
      bf16x8 af[4], bfr[4];
#pragma unroll
      for (int i = 0; i < 4; ++i) {
        af[i] = *(const bf16x8*)&As[(wm + i * 16 + lr) * 64 + ks * 32 + quad * 8];
        bfr[i] = *(const bf16x8*)&Bs[(wn + i * 16 + lr) * 64 + ks * 32 + quad * 8];
      }
#pragma unroll
      for (int i = 0; i < 4; ++i)
#pragma unroll
        for (int j = 0; j < 4; ++j)
          acc[i][j] = __builtin_amdgcn_mfma_f32_16x16x32_bf16(af[i], bfr[j], acc[i][j], 0, 0, 0);
    }
    __syncthreads();
  }
  if (QKV) {
    const int sel = n0 >> 10;                    // whole block stays in one of q/k/v
    u16* dst = (sel == 0) ? qo : ((sel == 1) ? ko : vo);
    const int cb = (n0 & 1023) + wn;
#pragma unroll
    for (int i = 0; i < 4; ++i)
#pragma unroll
      for (int j = 0; j < 4; ++j)
#pragma unroll
        for (int rr = 0; rr < 4; ++rr) {
          int row = m0 + wm + i * 16 + quad * 4 + rr;
          float v = acc[i][j][rr];
          if (sel < 2) v = fmaxf(v, 0.0f) + FLA_EPS;   // fused feature map
          dst[(size_t)row * 1024 + cb + j * 16 + lr] = f2b(v);
        }
  } else {
#pragma unroll
    for (int i = 0; i < 4; ++i)
#pragma unroll
      for (int j = 0; j < 4; ++j) {
        int col = n0 + wn + j * 16 + lr;
#pragma unroll
        for (int rr = 0; rr < 4; ++rr) {
          int row = m0 + wm + i * 16 + quad * 4 + rr;
          Cf[(size_t)row * 1024 + col] = acc[i][j][rr] + bias[col];
        }
      }
  }
}

// ---------------- kv partials: part[bh][sub][d][f] = sum_n kf[n][f]*v[n][d] over 256 n ----------------
__global__ void __launch_bounds__(256) kv_partial(const u16* __restrict__ kf,
                                                  const u16* __restrict__ v,
                                                  float* __restrict__ part,
                                                  float* __restrict__ ksum_p) {
  const int t = threadIdx.x;
  const int bh = blockIdx.x, b = bh >> 4, h = bh & 15;
  const int w = t >> 6, l = t & 63;
  const int sub = blockIdx.y * 4 + w;
  const int f0 = (l >> 3) * 8, d0 = (l & 7) * 8;
  const size_t rowbase = ((size_t)b * 8192 + (size_t)sub * 256) * 1024 + h * 64;
  float acc[8][8] = {};
  float ks[8] = {};
#pragma unroll 2
  for (int n = 0; n < 256; ++n) {
    u16x8 ka = *(const u16x8*)(kf + rowbase + (size_t)n * 1024 + f0);
    u16x8 va = *(const u16x8*)(v + rowbase + (size_t)n * 1024 + d0);
    float kff[8], vf[8];
#pragma unroll
    for (int i = 0; i < 8; ++i) { kff[i] = b2f(ka[i]); vf[i] = b2f(va[i]); }
#pragma unroll
    for (int i = 0; i < 8; ++i) {
      ks[i] += kff[i];
#pragma unroll
      for (int j = 0; j < 8; ++j) acc[i][j] = fmaf(kff[i], vf[j], acc[i][j]);
    }
  }
  float* pb = part + ((size_t)bh * 32 + sub) * 4096;
#pragma unroll
  for (int j = 0; j < 8; ++j)
#pragma unroll
    for (int i = 0; i < 8; i += 4) {
      f32x4 vv = { acc[i][j], acc[i + 1][j], acc[i + 2][j], acc[i + 3][j] };
      *(f32x4*)(pb + (d0 + j) * 64 + f0 + i) = vv;
    }
  if (d0 == 0) {
    float* kp = ksum_p + ((size_t)bh * 32 + sub) * 64 + f0;
    f32x4 a = { ks[0], ks[1], ks[2], ks[3] }, bq = { ks[4], ks[5], ks[6], ks[7] };
    *(f32x4*)(kp) = a; *(f32x4*)(kp + 4) = bq;
  }
}

__global__ void __launch_bounds__(256) reduce_kv(const float* __restrict__ part,
                                                 float* __restrict__ kvT) {
  int i = blockIdx.x * 256 + threadIdx.x;
  int bh = i >> 12, dfi = i & 4095;
  const float* p = part + (size_t)bh * 32 * 4096 + dfi;
  float s = 0.f;
#pragma unroll
  for (int sub = 0; sub < 32; ++sub) s += p[(size_t)sub * 4096];
  kvT[i] = s;
}

// ---------------- num/den + normalize ----------------
__global__ void __launch_bounds__(256) num_den(const u16* __restrict__ qf,
                                               const float* __restrict__ kvT,
                                               const float* __restrict__ ksum_p,
                                               u16* __restrict__ outI) {
  __shared__ __align__(16) u16 As[128 * 64];
  __shared__ __align__(16) u16 Bs[64 * 64];
  __shared__ float ksum_s[64];
  __shared__ float den_s[128];
  const int t = threadIdx.x;
  const size_t tok0 = (size_t)blockIdx.x * 128;
  const int h = blockIdx.y;
  const int bh = (blockIdx.x >> 6) * 16 + h;
  const int w = t >> 6, l = t & 63, quad = l >> 4, lr = l & 15;
  const int trow = t >> 3, tcol = (t & 7) * 8;
#pragma unroll
  for (int i = 0; i < 4; ++i) {
    int r = i * 32 + trow;
    g2l16(qf + (tok0 + r) * 1024 + h * 64 + tcol, &As[r * 64 + tcol]);
  }
  {
    const float* kvb = kvT + (size_t)bh * 4096;
    int d = t >> 2, cb = (t & 3) * 16;
    u16x8 o0, o1;
#pragma unroll
    for (int q4 = 0; q4 < 2; ++q4) {
      f32x4 vv = *(const f32x4*)(kvb + d * 64 + cb + q4 * 4);
      o0[q4 * 4 + 0] = f2b(vv[0]); o0[q4 * 4 + 1] = f2b(vv[1]);
      o0[q4 * 4 + 2] = f2b(vv[2]); o0[q4 * 4 + 3] = f2b(vv[3]);
    }
#pragma unroll
    for (int q4 = 0; q4 < 2; ++q4) {
      f32x4 vv = *(const f32x4*)(kvb + d * 64 + cb + 8 + q4 * 4);
      o1[q4 * 4 + 0] = f2b(vv[0]); o1[q4 * 4 + 1] = f2b(vv[1]);
      o1[q4 * 4 + 2] = f2b(vv[2]); o1[q4 * 4 + 3] = f2b(vv[3]);
    }
    *(u16x8*)&Bs[d * 64 + cb] = o0;
    *(u16x8*)&Bs[d * 64 + cb + 8] = o1;
  }
  if (t < 64) {
    float s = 0.f;
    const float* kp = ksum_p + (size_t)bh * 32 * 64 + t;
#pragma unroll
    for (int sub = 0; sub < 32; ++sub) s += kp[(size_t)sub * 64];
    ksum_s[t] = s;
  }
  __syncthreads();
  if (t < 128) {
    float d = FLA_EPS;
#pragma unroll
    for (int jj = 0; jj < 64; ++jj) {
      int f = (t + jj) & 63;
      d += b2f(As[t * 64 + f]) * ksum_s[f];
    }
    den_s[t] = d;
  }
  __syncthreads();
  f32x4 acc[2][4] = {};
  const int wrow = w * 32;
#pragma unroll
  for (int ks = 0; ks < 2; ++ks) {
    bf16x8 af[2], bfr[4];
#pragma unroll
    for (int i = 0; i < 2; ++i)
      af[i] = *(const bf16x8*)&As[(wrow + i * 16 + lr) * 64 + ks * 32 + quad * 8];
#pragma unroll
    for (int j = 0; j < 4; ++j)
      bfr[j] = *(const bf16x8*)&Bs[(j * 16 + lr) * 64 + ks * 32 + quad * 8];
#pragma unroll
    for (int i = 0; i < 2; ++i)
#pragma unroll
      for (int j = 0; j < 4; ++j)
        acc[i][j] = __builtin_amdgcn_mfma_f32_16x16x32_bf16(af[i], bfr[j], acc[i][j], 0, 0, 0);
  }
#pragma unroll
  for (int i = 0; i < 2; ++i)
#pragma unroll
    for (int j = 0; j < 4; ++j)
#pragma unroll
      for (int rr = 0; rr < 4; ++rr) {
        int rloc = wrow + i * 16 + quad * 4 + rr;
        float v = acc[i][j][rr] / den_s[rloc];
        outI[(tok0 + rloc) * 1024 + h * 64 + j * 16 + lr] = f2b(v);
      }
}

extern "C" void kernel_launch(void* const* d_in, const int* in_sizes, int n_in,
                              void* d_out, int out_size, void* d_ws, size_t ws_size,
                              hipStream_t stream) {
  const float* x    = (const float*)d_in[0];
  const float* Wq   = (const float*)d_in[1];
  const float* Wk   = (const float*)d_in[2];
  const float* Wv   = (const float*)d_in[3];
  const float* proj = (const float*)d_in[4];
  const float* Wo   = (const float*)d_in[5];
  const float* bo   = (const float*)d_in[6];
  float* out = (float*)d_out;

  char* ws = (char*)d_ws;
  const size_t SZ = 1ull << 26;                 // 64 MiB
  u16* xb     = (u16*)(ws + 0);                 // x bf16; later reused as out_inner
  u16* qb     = (u16*)(ws + SZ);                // qf
  u16* kb     = (u16*)(ws + 2 * SZ);            // kf
  u16* vb     = (u16*)(ws + 3 * SZ);            // v
  u16* WqkvT  = (u16*)(ws + 4 * SZ);            // [3072][1024] bf16 (6 MiB)
  u16* woT    = (u16*)(ws + 4 * SZ + 0x600000); // 2 MiB
  float* part   = (float*)(ws + 4 * SZ + 0x800000);              // 32 MiB
  float* ksum_p = (float*)(ws + 4 * SZ + 0x800000 + 0x2000000);  // 512 KiB
  float* kvT    = (float*)(ws + 4 * SZ + 0x800000 + 0x2080000);  // 1 MiB

  cast_f32_bf16<<<16384, 256, 0, stream>>>(x, xb);
  fold_w<<<dim3(16, 16, 2), 256, 0, stream>>>(Wq, Wk, proj, WqkvT);
  transpose_cast<<<dim3(16, 16), 256, 0, stream>>>(Wv, WqkvT + (size_t)2048 * 1024, 1024);
  transpose_cast<<<dim3(16, 16), 256, 0, stream>>>(Wo, woT, 1024);
  // fused QKV projection + feature map (relu+eps on q,k)
  gemm_swz<3, true><<<dim3(256, 24), 256, 0, stream>>>(xb, WqkvT, qb, kb, vb, nullptr, nullptr);
  // kv + ksum reduction
  kv_partial<<<dim3(64, 8), 256, 0, stream>>>(kb, vb, part, ksum_p);
  reduce_kv<<<1024, 256, 0, stream>>>(part, kvT);
  // num/den + normalize -> out_inner (reuse xb)
  num_den<<<dim3(256, 16), 256, 0, stream>>>(qb, kvT, ksum_p, xb);
  // output projection + bias
  gemm_swz<1, false><<<dim3(256, 8), 256, 0, stream>>>(xb, woT, nullptr, nullptr, nullptr, out, bo);
}

// Round 3
// 798.129 us; speedup vs baseline: 1.1140x; 1.0176x over previous
//
#include <hip/hip_runtime.h>

typedef unsigned short u16;
typedef unsigned int u32;
typedef __attribute__((ext_vector_type(4))) float f32x4;
typedef __attribute__((ext_vector_type(4))) u16 u16x4;
typedef __attribute__((ext_vector_type(8))) u16 u16x8;
typedef __attribute__((ext_vector_type(8))) __bf16 bf16x8;

#define FLA_EPS 1e-6f

__device__ __forceinline__ u16 f2b(float f) {
  union { float f; u32 u; } v; v.f = f;
  u32 r = v.u + 0x7FFFu + ((v.u >> 16) & 1u);
  return (u16)(r >> 16);
}
__device__ __forceinline__ float b2f(u16 h) {
  union { u32 u; float f; } v; v.u = ((u32)h) << 16; return v.f;
}
__device__ __forceinline__ void g2l16(const void* g, void* l) {
  __builtin_amdgcn_global_load_lds((__attribute__((address_space(1))) void*)g,
                                   (__attribute__((address_space(3))) void*)l,
                                   16, 0, 0);
}

// ---------------- cast x fp32 -> bf16 ----------------
__global__ void __launch_bounds__(256) cast_f32_bf16(const float* __restrict__ in,
                                                     u16* __restrict__ out) {
  size_t i = (size_t)blockIdx.x * 256 + threadIdx.x;
  const f32x4* p = (const f32x4*)in + i * 2;
  f32x4 a = p[0], b = p[1];
  u16x8 r;
  r[0] = f2b(a[0]); r[1] = f2b(a[1]); r[2] = f2b(a[2]); r[3] = f2b(a[3]);
  r[4] = f2b(b[0]); r[5] = f2b(b[1]); r[6] = f2b(b[2]); r[7] = f2b(b[3]);
  ((u16x8*)out)[i] = r;
}

// ---------------- transpose + cast: Wt[n][k] = bf16(W[k][n]) ----------------
__global__ void __launch_bounds__(256) transpose_cast(const float* __restrict__ W,
                                                      u16* __restrict__ Wt, int dim) {
  __shared__ float tile[64][65];
  const int t = threadIdx.x;
  const int k0 = blockIdx.x * 64, n0 = blockIdx.y * 64;
  const int r = t >> 4, c4 = (t & 15) * 4;
#pragma unroll
  for (int i = 0; i < 4; ++i) {
    f32x4 vv = *(const f32x4*)(W + (size_t)(k0 + r + i * 16) * dim + n0 + c4);
    tile[r + i * 16][c4 + 0] = vv[0];
    tile[r + i * 16][c4 + 1] = vv[1];
    tile[r + i * 16][c4 + 2] = vv[2];
    tile[r + i * 16][c4 + 3] = vv[3];
  }
  __syncthreads();
#pragma unroll
  for (int i = 0; i < 4; ++i) {
    int nrow = r + i * 16;
    u16x4 o;
#pragma unroll
    for (int j = 0; j < 4; ++j) o[j] = f2b(tile[c4 + j][nrow]);
    *(u16x4*)(Wt + (size_t)(n0 + nrow) * dim + k0 + c4) = o;
  }
}

// ---------------- fold proj into Wq/Wk ----------------
__global__ void __launch_bounds__(256) fold_w(const float* __restrict__ Wq,
                                              const float* __restrict__ Wk,
                                              const float* __restrict__ proj,
                                              u16* __restrict__ WqkvT) {
  __shared__ float Wt[64][65];
  __shared__ float P[64][64];
  const int t = threadIdx.x;
  const int kbase = blockIdx.x * 64, h = blockIdx.y, sel = blockIdx.z;
  const float* W = sel ? Wk : Wq;
  {
    int row = t >> 2, cb = (t & 3) * 16;
#pragma unroll
    for (int i = 0; i < 4; ++i) {
      f32x4 vv = *(const f32x4*)(W + (size_t)(kbase + row) * 1024 + h * 64 + cb + i * 4);
      Wt[row][cb + i * 4 + 0] = vv[0]; Wt[row][cb + i * 4 + 1] = vv[1];
      Wt[row][cb + i * 4 + 2] = vv[2]; Wt[row][cb + i * 4 + 3] = vv[3];
      f32x4 pp = *(const f32x4*)(proj + (size_t)row * 64 + cb + i * 4);
      P[row][cb + i * 4 + 0] = pp[0]; P[row][cb + i * 4 + 1] = pp[1];
      P[row][cb + i * 4 + 2] = pp[2]; P[row][cb + i * 4 + 3] = pp[3];
    }
  }
  __syncthreads();
  const int kk = t & 63, fg = (t >> 6) * 16;
  float acc[16] = {};
  for (int d = 0; d < 64; ++d) {
    float w = Wt[kk][d];
#pragma unroll
    for (int ff = 0; ff < 16; ++ff) acc[ff] = fmaf(w, P[d][fg + ff], acc[ff]);
  }
#pragma unroll
  for (int ff = 0; ff < 16; ++ff)
    WqkvT[(size_t)(sel * 1024 + h * 64 + fg + ff) * 1024 + kbase + kk] = f2b(acc[ff]);
}

// ---------------- 128x128 bf16 MFMA GEMM, XCD-aware swizzled block order ----------------
// M hardcoded 32768 (256 m-blocks = 32 m-groups of 8; 4 m-groups per XCD).
// NGN = N/1024 (n-groups of 8 blocks). QKV: NGN=3 -> q/k get relu+eps; final: NGN=1 fp32+bias.
template <int NGN, bool QKV>
__global__ void __launch_bounds__(256) gemm_swz(const u16* __restrict__ A,
                                                const u16* __restrict__ Bt,
                                                u16* __restrict__ qo, u16* __restrict__ ko,
                                                u16* __restrict__ vo,
                                                float* __restrict__ Cf,
                                                const float* __restrict__ bias) {
  __shared__ __align__(16) u16 As[128 * 64];
  __shared__ __align__(16) u16 Bs[128 * 64];
  const int t = threadIdx.x;
  // XCD-aware swizzle: consecutive flat ids round-robin XCDs (flat&7 = xcd).
  // slot = residency order on one XCD; 64 slots (2 blocks/CU x 32 CU) = one 8x8 (m,n)
  // group -> per-XCD L2 working set = 8 A-strips + 8 B-strips = 4 MB (fits L2).
  // Groups ordered gn-major so the B-strip is reused across 4 consecutive groups.
  const int flat = blockIdx.x + blockIdx.y * gridDim.x;
  const int xcd = flat & 7, slot = flat >> 3;
  const int grp = slot >> 6, pos = slot & 63;      // grp in [0, NGN*4)
  const int gn = grp >> 2, gmi = grp & 3;
  const int gm = xcd * 4 + gmi;                    // 0..31
  const int m0 = (gm * 8 + (pos & 7)) * 128;
  const int n0 = (gn * 8 + (pos >> 3)) * 128;
  const int w = t >> 6, l = t & 63, quad = l >> 4, lr = l & 15;
  const int wm = (w >> 1) * 64, wn = (w & 1) * 64;
  const int trow = t >> 3, tcol = (t & 7) * 8;
  f32x4 acc[4][4] = {};
  for (int k0 = 0; k0 < 1024; k0 += 64) {
#pragma unroll
    for (int i = 0; i < 4; ++i) {
      int r = i * 32 + trow;
      g2l16(A + (size_t)(m0 + r) * 1024 + k0 + tcol, &As[r * 64 + tcol]);
      g2l16(Bt + (size_t)(n0 + r) * 1024 + k0 + tcol, &Bs[r * 64 + tcol]);
    }
    __syncthreads();
#pragma unroll
    for (int ks = 0; ks < 2; ++ks) {
      bf16x8 af[4], bfr[4];
#pragma unroll
      for (int i = 0; i < 4; ++i) {
        af[i] = *(const bf16x8*)&As[(wm + i * 16 + lr) * 64 + ks * 32 + quad * 8];
        bfr[i] = *(const bf16x8*)&Bs[(wn + i * 16 + lr) * 64 + ks * 32 + quad * 8];
      }
#pragma unroll
      for (int i = 0; i < 4; ++i)
#pragma unroll
        for (int j = 0; j < 4; ++j)
          acc[i][j] = __builtin_amdgcn_mfma_f32_16x16x32_bf16(af[i], bfr[j], acc[i][j], 0, 0, 0);
    }
    __syncthreads();
  }
  if (QKV) {
    const int sel = n0 >> 10;
    u16* dst = (sel == 0) ? qo : ((sel == 1) ? ko : vo);
    const int cb = (n0 & 1023) + wn;
#pragma unroll
    for (int i = 0; i < 4; ++i)
#pragma unroll
      for (int j = 0; j < 4; ++j)
#pragma unroll
        for (int rr = 0; rr < 4; ++rr) {
          int row = m0 + wm + i * 16 + quad * 4 + rr;
          float v = acc[i][j][rr];
          if (sel < 2) v = fmaxf(v, 0.0f) + FLA_EPS;
          dst[(size_t)row * 1024 + cb + j * 16 + lr] = f2b(v);
        }
  } else {
#pragma unroll
    for (int i = 0; i < 4; ++i)
#pragma unroll
      for (int j = 0; j < 4; ++j) {
        int col = n0 + wn + j * 16 + lr;
#pragma unroll
        for (int rr = 0; rr < 4; ++rr) {
          int row = m0 + wm + i * 16 + quad * 4 + rr;
          Cf[(size_t)row * 1024 + col] = acc[i][j][rr] + bias[col];
        }
      }
  }
}

// ---------------- kv partials ----------------
__global__ void __launch_bounds__(256) kv_partial(const u16* __restrict__ kf,
                                                  const u16* __restrict__ v,
                                                  float* __restrict__ part,
                                                  float* __restrict__ ksum_p) {
  const int t = threadIdx.x;
  const int bh = blockIdx.x, b = bh >> 4, h = bh & 15;
  const int w = t >> 6, l = t & 63;
  const int sub = blockIdx.y * 4 + w;
  const int f0 = (l >> 3) * 8, d0 = (l & 7) * 8;
  const size_t rowbase = ((size_t)b * 8192 + (size_t)sub * 256) * 1024 + h * 64;
  float acc[8][8] = {};
  float ks[8] = {};
#pragma unroll 2
  for (int n = 0; n < 256; ++n) {
    u16x8 ka = *(const u16x8*)(kf + rowbase + (size_t)n * 1024 + f0);
    u16x8 va = *(const u16x8*)(v + rowbase + (size_t)n * 1024 + d0);
    float kff[8], vf[8];
#pragma unroll
    for (int i = 0; i < 8; ++i) { kff[i] = b2f(ka[i]); vf[i] = b2f(va[i]); }
#pragma unroll
    for (int i = 0; i < 8; ++i) {
      ks[i] += kff[i];
#pragma unroll
      for (int j = 0; j < 8; ++j) acc[i][j] = fmaf(kff[i], vf[j], acc[i][j]);
    }
  }
  float* pb = part + ((size_t)bh * 32 + sub) * 4096;
#pragma unroll
  for (int j = 0; j < 8; ++j)
#pragma unroll
    for (int i = 0; i < 8; i += 4) {
      f32x4 vv = { acc[i][j], acc[i + 1][j], acc[i + 2][j], acc[i + 3][j] };
      *(f32x4*)(pb + (d0 + j) * 64 + f0 + i) = vv;
    }
  if (d0 == 0) {
    float* kp = ksum_p + ((size_t)bh * 32 + sub) * 64 + f0;
    f32x4 a = { ks[0], ks[1], ks[2], ks[3] }, bq = { ks[4], ks[5], ks[6], ks[7] };
    *(f32x4*)(kp) = a; *(f32x4*)(kp + 4) = bq;
  }
}

__global__ void __launch_bounds__(256) reduce_kv(const float* __restrict__ part,
                                                 float* __restrict__ kvT) {
  int i = blockIdx.x * 256 + threadIdx.x;
  int bh = i >> 12, dfi = i & 4095;
  const float* p = part + (size_t)bh * 32 * 4096 + dfi;
  float s = 0.f;
#pragma unroll
  for (int sub = 0; sub < 32; ++sub) s += p[(size_t)sub * 4096];
  kvT[i] = s;
}

// ---------------- num/den + normalize ----------------
__global__ void __launch_bounds__(256) num_den(const u16* __restrict__ qf,
                                               const float* __restrict__ kvT,
                                               const float* __restrict__ ksum_p,
                                               u16* __restrict__ outI) {
  __shared__ __align__(16) u16 As[128 * 64];
  __shared__ __align__(16) u16 Bs[64 * 64];
  __shared__ float ksum_s[64];
  __shared__ float den_s[128];
  const int t = threadIdx.x;
  const size_t tok0 = (size_t)blockIdx.x * 128;
  const int h = blockIdx.y;
  const int bh = (blockIdx.x >> 6) * 16 + h;
  const int w = t >> 6, l = t & 63, quad = l >> 4, lr = l & 15;
  const int trow = t >> 3, tcol = (t & 7) * 8;
#pragma unroll
  for (int i = 0; i < 4; ++i) {
    int r = i * 32 + trow;
    g2l16(qf + (tok0 + r) * 1024 + h * 64 + tcol, &As[r * 64 + tcol]);
  }
  {
    const float* kvb = kvT + (size_t)bh * 4096;
    int d = t >> 2, cb = (t & 3) * 16;
    u16x8 o0, o1;
#pragma unroll
    for (int q4 = 0; q4 < 2; ++q4) {
      f32x4 vv = *(const f32x4*)(kvb + d * 64 + cb + q4 * 4);
      o0[q4 * 4 + 0] = f2b(vv[0]); o0[q4 * 4 + 1] = f2b(vv[1]);
      o0[q4 * 4 + 2] = f2b(vv[2]); o0[q4 * 4 + 3] = f2b(vv[3]);
    }
#pragma unroll
    for (int q4 = 0; q4 < 2; ++q4) {
      f32x4 vv = *(const f32x4*)(kvb + d * 64 + cb + 8 + q4 * 4);
      o1[q4 * 4 + 0] = f2b(vv[0]); o1[q4 * 4 + 1] = f2b(vv[1]);
      o1[q4 * 4 + 2] = f2b(vv[2]); o1[q4 * 4 + 3] = f2b(vv[3]);
    }
    *(u16x8*)&Bs[d * 64 + cb] = o0;
    *(u16x8*)&Bs[d * 64 + cb + 8] = o1;
  }
  if (t < 64) {
    float s = 0.f;
    const float* kp = ksum_p + (size_t)bh * 32 * 64 + t;
#pragma unroll
    for (int sub = 0; sub < 32; ++sub) s += kp[(size_t)sub * 64];
    ksum_s[t] = s;
  }
  __syncthreads();
  if (t < 128) {
    float d = FLA_EPS;
#pragma unroll
    for (int jj = 0; jj < 64; ++jj) {
      int f = (t + jj) & 63;
      d += b2f(As[t * 64 + f]) * ksum_s[f];
    }
    den_s[t] = d;
  }
  __syncthreads();
  f32x4 acc[2][4] = {};
  const int wrow = w * 32;
#pragma unroll
  for (int ks = 0; ks < 2; ++ks) {
    bf16x8 af[2], bfr[4];
#pragma unroll
    for (int i = 0; i < 2; ++i)
      af[i] = *(const bf16x8*)&As[(wrow + i * 16 + lr) * 64 + ks * 32 + quad * 8];
#pragma unroll
    for (int j = 0; j < 4; ++j)
      bfr[j] = *(const bf16x8*)&Bs[(j * 16 + lr) * 64 + ks * 32 + quad * 8];
#pragma unroll
    for (int i = 0; i < 2; ++i)
#pragma unroll
      for (int j = 0; j < 4; ++j)
        acc[i][j] = __builtin_amdgcn_mfma_f32_16x16x32_bf16(af[i], bfr[j], acc[i][j], 0, 0, 0);
  }
#pragma unroll
  for (int i = 0; i < 2; ++i)
#pragma unroll
    for (int j = 0; j < 4; ++j)
#pragma unroll
      for (int rr = 0; rr < 4; ++rr) {
        int rloc = wrow + i * 16 + quad * 4 + rr;
        float v = acc[i][j][rr] / den_s[rloc];
        outI[(tok0 + rloc) * 1024 + h * 64 + j * 16 + lr] = f2b(v);
      }
}

extern "C" void kernel_launch(void* const* d_in, const int* in_sizes, int n_in,
                              void* d_out, int out_size, void* d_ws, size_t ws_size,
                              hipStream_t stream) {
  const float* x    = (const float*)d_in[0];
  const float* Wq   = (const float*)d_in[1];
  const float* Wk   = (const float*)d_in[2];
  const float* Wv   = (const float*)d_in[3];
  const float* proj = (const float*)d_in[4];
  const float* Wo   = (const float*)d_in[5];
  const float* bo   = (const float*)d_in[6];
  float* out = (float*)d_out;

  char* ws = (char*)d_ws;
  const size_t SZ = 1ull << 26;
  u16* xb     = (u16*)(ws + 0);
  u16* qb     = (u16*)(ws + SZ);
  u16* kb     = (u16*)(ws + 2 * SZ);
  u16* vb     = (u16*)(ws + 3 * SZ);
  u16* WqkvT  = (u16*)(ws + 4 * SZ);
  u16* woT    = (u16*)(ws + 4 * SZ + 0x600000);
  float* part   = (float*)(ws + 4 * SZ + 0x800000);
  float* ksum_p = (float*)(ws + 4 * SZ + 0x800000 + 0x2000000);
  float* kvT    = (float*)(ws + 4 * SZ + 0x800000 + 0x2080000);

  cast_f32_bf16<<<16384, 256, 0, stream>>>(x, xb);
  fold_w<<<dim3(16, 16, 2), 256, 0, stream>>>(Wq, Wk, proj, WqkvT);
  transpose_cast<<<dim3(16, 16), 256, 0, stream>>>(Wv, WqkvT + (size_t)2048 * 1024, 1024);
  transpose_cast<<<dim3(16, 16), 256, 0, stream>>>(Wo, woT, 1024);
  gemm_swz<3, true><<<dim3(256, 24), 256, 0, stream>>>(xb, WqkvT, qb, kb, vb, nullptr, nullptr);
  kv_partial<<<dim3(64, 8), 256, 0, stream>>>(kb, vb, part, ksum_p);
  reduce_kv<<<1024, 256, 0, stream>>>(part, kvT);
  num_den<<<dim3(256, 16), 256, 0, stream>>>(qb, kvT, ksum_p, xb);
  gemm_swz<1, false><<<dim3(256, 8), 256, 0, stream>>>(xb, woT, nullptr, nullptr, nullptr, out, bo);
}